// Round 11
// baseline (89.063 us; speedup 1.0000x reference)
//
#include <hip/hip_runtime.h>
#include <cstdint>
#include <cstddef>

#define NN 50000
#define FF 128
#define CC 128
#define KK 10

constexpr int TILES_P = NN / 16;            // 3125 row-tiles per protein
constexpr size_t NC = (size_t)NN * CC;      // 6.4M elements per protein

typedef __bf16 bf16x8 __attribute__((ext_vector_type(8)));
typedef float  f32x4  __attribute__((ext_vector_type(4)));
typedef float  f32x2  __attribute__((ext_vector_type(2)));

__device__ __forceinline__ unsigned f2bf_u(float f) {
  union { float f; unsigned u; } x; x.f = f;
  unsigned r = x.u + 0x7fffu + ((x.u >> 16) & 1u);   // RNE
  return r >> 16;
}

// ---------------------------------------------------------------------------
// Phase 1 (R9-exact): S = Z@Wsv -> ws (bf16); Rs,Rd -> ws (e4m3, HW cvt).
// Wide-segment stores (B-col mapping col0+2*l15+j): S = 1 dword (64B
// segments), Rs/Rd = 1 ushort (32B segments). Plain stores (R10 showed NT
// is a no-op here).
// ---------------------------------------------------------------------------
__global__ __launch_bounds__(256, 2)
void gemm3_kernel(const float* __restrict__ Z1, const float* __restrict__ Z2,
                  const float* __restrict__ Wsv, const float* __restrict__ Wsr,
                  const float* __restrict__ Wdr,
                  unsigned short* __restrict__ tblS, unsigned char* __restrict__ tbl8)
{
  const int tid  = threadIdx.x;
  const int wave = tid >> 6;
  const int lane = tid & 63;
  const int l15  = lane & 15;
  const int lg   = lane >> 4;
  const int col0 = wave * 32;

  const float* Wm[3] = { Wsv, Wsr, Wdr };
  bf16x8 b[3][2][4];
#pragma unroll
  for (int m = 0; m < 3; ++m) {
    const float* __restrict__ W = Wm[m];
#pragma unroll
    for (int j = 0; j < 2; ++j) {
      const int col = col0 + 2 * l15 + j;
#pragma unroll
      for (int s = 0; s < 4; ++s) {
        bf16x8 f;
#pragma unroll
        for (int e = 0; e < 8; ++e) {
          const int k = s * 32 + (e >> 2) * 16 + lg * 4 + (e & 3);
          f[e] = (__bf16)W[k * CC + col];
        }
        b[m][j][s] = f;
      }
    }
  }

  const int total = 2 * TILES_P;
  for (int t = blockIdx.x; t < total; t += gridDim.x) {
    const int p    = (t >= TILES_P) ? 1 : 0;
    const int row0 = (t - p * TILES_P) * 16;
    const float* __restrict__ Z = p ? Z2 : Z1;
    const float* zrow = Z + (size_t)(row0 + l15) * FF;

    bf16x8 a[4];
#pragma unroll
    for (int s = 0; s < 4; ++s) {
      const f32x4 ha = *(const f32x4*)(zrow + s * 32 + lg * 4);
      const f32x4 hb = *(const f32x4*)(zrow + s * 32 + 16 + lg * 4);
      bf16x8 f;
      f[0] = (__bf16)ha.x; f[1] = (__bf16)ha.y; f[2] = (__bf16)ha.z; f[3] = (__bf16)ha.w;
      f[4] = (__bf16)hb.x; f[5] = (__bf16)hb.y; f[6] = (__bf16)hb.z; f[7] = (__bf16)hb.w;
      a[s] = f;
    }

    f32x4 acc[3][2] = {};
#pragma unroll
    for (int s = 0; s < 4; ++s)
#pragma unroll
      for (int m = 0; m < 3; ++m)
#pragma unroll
        for (int j = 0; j < 2; ++j)
          acc[m][j] = __builtin_amdgcn_mfma_f32_16x16x32_bf16(a[s], b[m][j][s], acc[m][j], 0, 0, 0);

    unsigned short* tS  = tblS + (size_t)p * NC;
    unsigned char*  tRs = tbl8 + (size_t)(2 * p + 0) * NC;
    unsigned char*  tRd = tbl8 + (size_t)(2 * p + 1) * NC;
#pragma unroll
    for (int r = 0; r < 4; ++r) {
      const int row = row0 + lg * 4 + r;
      const size_t o = (size_t)row * CC + col0 + 2 * l15;   // cols 2*l15, 2*l15+1

      *(unsigned*)(tS + o) = f2bf_u(acc[0][0][r]) | (f2bf_u(acc[0][1][r]) << 16);

      const int pks = __builtin_amdgcn_cvt_pk_fp8_f32(acc[1][0][r], acc[1][1][r], 0, false);
      *(unsigned short*)(tRs + o) = (unsigned short)pks;

      const int pkd = __builtin_amdgcn_cvt_pk_fp8_f32(acc[2][0][r], acc[2][1][r], 0, false);
      *(unsigned short*)(tRd + o) = (unsigned short)pkd;
    }
  }
}

// ---------------------------------------------------------------------------
// Phase 1.5: PREHEAT — stream the fp8 table region sequentially so the lines
// settle into L3 before agg's random gathers. R9/R10 coupling post-mortem:
// fast gemm (25 µs) => agg 59-61 µs; slow gemm (61-78 µs) => agg ~33 µs, with
// identical agg code and FETCH. FETCH counts L2->fabric and can't tell L3-hit
// from HBM-miss: slow gemm trickles table lines into L3 during its runtime,
// fast gemm's end-of-kernel bulk writeback leaves them HBM-resident. This
// ~6 µs sequential read (kept live via asm, DCE rule) restores L3 residency.
// ---------------------------------------------------------------------------
__global__ __launch_bounds__(256)
void preheat_kernel(const f32x4* __restrict__ t, int n4)
{
  float acc = 0.f;
  for (int i = blockIdx.x * 256 + threadIdx.x; i < n4; i += gridDim.x * 256) {
    const f32x4 v = t[i];
    acc += v.x + v.y + v.z + v.w;
  }
  asm volatile("" :: "v"(acc));   // keep loads live; no store
}

// ---------------------------------------------------------------------------
// Phase 2: one wave per node, lane covers 2 cols (ushort = 2 x e4m3).
// Node id in SGPR -> scalar index loads; 20 gathers issued as one batch;
// the asm memory barrier FORCES all loads before any use (keeps MLP).
// Decode via HW v_cvt_pk_f32_fp8. BYTE-IDENTICAL to R9/R10.
// ---------------------------------------------------------------------------
__global__ __launch_bounds__(256)
void agg_kernel(const int* __restrict__ same1, const int* __restrict__ diff1,
                const int* __restrict__ same2, const int* __restrict__ diff2,
                const unsigned short* __restrict__ tblS,
                const unsigned char* __restrict__ tbl8,
                float* __restrict__ out)
{
  const int lane = threadIdx.x & 63;
  const int g    = __builtin_amdgcn_readfirstlane(blockIdx.x * 4 + (threadIdx.x >> 6));
  const int p    = (g >= NN) ? 1 : 0;
  const int node = g - p * NN;
  const int* __restrict__ same = p ? same2 : same1;
  const int* __restrict__ diff = p ? diff2 : diff1;
  const unsigned char* __restrict__ tRs = tbl8 + (size_t)(2 * p + 0) * NC;
  const unsigned char* __restrict__ tRd = tbl8 + (size_t)(2 * p + 1) * NC;

  int idx[2 * KK];
#pragma unroll
  for (int k = 0; k < KK; ++k) {
    idx[k]      = same[node * KK + k];
    idx[KK + k] = diff[node * KK + k];
  }

  unsigned val[2 * KK];
#pragma unroll
  for (int i = 0; i < 2 * KK; ++i) {
    const unsigned char* __restrict__ t = (i < KK) ? tRs : tRd;
    const int ic = idx[i] < 0 ? 0 : idx[i];
    val[i] = *(const unsigned short*)(t + (size_t)ic * CC + lane * 2);
  }
  const size_t o = (size_t)g * CC + (size_t)(lane * 2);
  const unsigned su = *(const unsigned*)(tblS + o);

  asm volatile("" ::: "memory");   // keep all 20 gathers + S load in flight

  float s0 = 0.f, s1 = 0.f, d0 = 0.f, d1 = 0.f;
  int sc = 0, dc = 0;
#pragma unroll
  for (int i = 0; i < KK; ++i) {
    sc += (idx[i] >= 0);
    const unsigned u = (idx[i] >= 0) ? val[i] : 0u;
    f32x2 pr = __builtin_amdgcn_cvt_pk_f32_fp8(u, false);
    s0 += pr.x; s1 += pr.y;
  }
#pragma unroll
  for (int i = KK; i < 2 * KK; ++i) {
    dc += (idx[i] >= 0);
    const unsigned u = (idx[i] >= 0) ? val[i] : 0u;
    f32x2 pr = __builtin_amdgcn_cvt_pk_f32_fp8(u, false);
    d0 += pr.x; d1 += pr.y;
  }

  union { unsigned u; float f; } slo, shi;
  slo.u = su << 16;
  shi.u = su & 0xFFFF0000u;

  const float fs = 1.f / (float)(sc > 0 ? sc : 1);
  const float fd = 1.f / (float)(dc > 0 ? dc : 1);
  const float vlo = slo.f + s0 * fs + d0 * fd;
  const float vhi = shi.f + s1 * fs + d1 * fd;
  f32x2 r;
  r.x = vlo > 0.f ? vlo : 0.f;
  r.y = vhi > 0.f ? vhi : 0.f;
  __builtin_nontemporal_store(r, (f32x2*)(out + o));
}

// ---------------------------------------------------------------------------
// Safety fallback if ws is too small: direct per-node recompute (slow, correct).
// ---------------------------------------------------------------------------
__global__ __launch_bounds__(128)
void fallback_kernel(const float* __restrict__ Z, const int* __restrict__ same,
                     const int* __restrict__ diff,
                     const float* __restrict__ Wsv, const float* __restrict__ Wsr,
                     const float* __restrict__ Wdr, float* __restrict__ out)
{
  const int node = blockIdx.x;
  const int c    = threadIdx.x;
  __shared__ float zs[FF];
  zs[c] = Z[(size_t)node * FF + c];
  __syncthreads();
  float sig = 0.f;
  for (int f = 0; f < FF; ++f) sig += zs[f] * Wsv[f * CC + c];

  float ssum = 0.f, dsum = 0.f;
  int scnt = 0, dcnt = 0;
  for (int k = 0; k < KK; ++k) {
    const int is = same[node * KK + k];
    if (is >= 0) {
      __syncthreads();
      zs[c] = Z[(size_t)is * FF + c];
      __syncthreads();
      float a = 0.f;
      for (int f = 0; f < FF; ++f) a += zs[f] * Wsr[f * CC + c];
      ssum += a; scnt++;
    }
  }
  for (int k = 0; k < KK; ++k) {
    const int id = diff[node * KK + k];
    if (id >= 0) {
      __syncthreads();
      zs[c] = Z[(size_t)id * FF + c];
      __syncthreads();
      float a = 0.f;
      for (int f = 0; f < FF; ++f) a += zs[f] * Wdr[f * CC + c];
      dsum += a; dcnt++;
    }
  }
  const float v = sig + ssum / (float)(scnt > 0 ? scnt : 1)
                      + dsum / (float)(dcnt > 0 ? dcnt : 1);
  out[(size_t)node * CC + c] = v > 0.f ? v : 0.f;
}

extern "C" void kernel_launch(void* const* d_in, const int* in_sizes, int n_in,
                              void* d_out, int out_size, void* d_ws, size_t ws_size,
                              hipStream_t stream)
{
  const float* Z1    = (const float*)d_in[0];
  const int*   same1 = (const int*)  d_in[1];
  const int*   diff1 = (const int*)  d_in[2];
  const float* Z2    = (const float*)d_in[3];
  const int*   same2 = (const int*)  d_in[4];
  const int*   diff2 = (const int*)  d_in[5];
  const float* Wsv   = (const float*)d_in[6];
  const float* Wsr   = (const float*)d_in[7];
  const float* Wdr   = (const float*)d_in[8];
  float* out = (float*)d_out;

  // ws layout: [ S bf16: 2*NC ushort | tables e4m3: 4*NC bytes ] = 8*NC bytes
  const size_t need = 8 * NC;
  unsigned short* tblS = (unsigned short*)d_ws;
  unsigned char*  tbl8 = (unsigned char*)d_ws + 2 * NC * sizeof(unsigned short);

  if (ws_size >= need) {
    gemm3_kernel<<<512, 256, 0, stream>>>(Z1, Z2, Wsv, Wsr, Wdr, tblS, tbl8);
    preheat_kernel<<<2048, 256, 0, stream>>>((const f32x4*)tbl8, (int)(NC / 4)); // 4*NC bytes / 16
    agg_kernel<<<(2 * NN) / 4, 256, 0, stream>>>(same1, diff1, same2, diff2,
                                                 tblS, tbl8, out);
  } else {
    fallback_kernel<<<NN, 128, 0, stream>>>(Z1, same1, diff1, Wsv, Wsr, Wdr, out);
    fallback_kernel<<<NN, 128, 0, stream>>>(Z2, same2, diff2, Wsv, Wsr, Wdr, out + NC);
  }
}

// Round 12
// 81.641 us; speedup vs baseline: 1.0909x; 1.0909x over previous
//
#include <hip/hip_runtime.h>
#include <cstdint>
#include <cstddef>

#define NN 50000
#define FF 128
#define CC 128
#define KK 10

constexpr int TILES_P = NN / 16;            // 3125 row-tiles per protein
constexpr size_t NC = (size_t)NN * CC;      // 6.4M elements per protein

typedef __bf16 bf16x8 __attribute__((ext_vector_type(8)));
typedef float  f32x4  __attribute__((ext_vector_type(4)));
typedef float  f32x2  __attribute__((ext_vector_type(2)));

__device__ __forceinline__ unsigned f2bf_u(float f) {
  union { float f; unsigned u; } x; x.f = f;
  unsigned r = x.u + 0x7fffu + ((x.u >> 16) & 1u);   // RNE
  return r >> 16;
}

// ---------------------------------------------------------------------------
// Phase 1 (R9-exact): S = Z@Wsv -> ws (bf16); Rs,Rd -> ws (e4m3, HW cvt).
// Wide-segment stores (B-col mapping col0+2*l15+j): S = 1 dword (64B
// segments), Rs/Rd = 1 ushort (32B segments). ~25 µs, at traffic floor.
// ---------------------------------------------------------------------------
__global__ __launch_bounds__(256, 2)
void gemm3_kernel(const float* __restrict__ Z1, const float* __restrict__ Z2,
                  const float* __restrict__ Wsv, const float* __restrict__ Wsr,
                  const float* __restrict__ Wdr,
                  unsigned short* __restrict__ tblS, unsigned char* __restrict__ tbl8)
{
  const int tid  = threadIdx.x;
  const int wave = tid >> 6;
  const int lane = tid & 63;
  const int l15  = lane & 15;
  const int lg   = lane >> 4;
  const int col0 = wave * 32;

  const float* Wm[3] = { Wsv, Wsr, Wdr };
  bf16x8 b[3][2][4];
#pragma unroll
  for (int m = 0; m < 3; ++m) {
    const float* __restrict__ W = Wm[m];
#pragma unroll
    for (int j = 0; j < 2; ++j) {
      const int col = col0 + 2 * l15 + j;
#pragma unroll
      for (int s = 0; s < 4; ++s) {
        bf16x8 f;
#pragma unroll
        for (int e = 0; e < 8; ++e) {
          const int k = s * 32 + (e >> 2) * 16 + lg * 4 + (e & 3);
          f[e] = (__bf16)W[k * CC + col];
        }
        b[m][j][s] = f;
      }
    }
  }

  const int total = 2 * TILES_P;
  for (int t = blockIdx.x; t < total; t += gridDim.x) {
    const int p    = (t >= TILES_P) ? 1 : 0;
    const int row0 = (t - p * TILES_P) * 16;
    const float* __restrict__ Z = p ? Z2 : Z1;
    const float* zrow = Z + (size_t)(row0 + l15) * FF;

    bf16x8 a[4];
#pragma unroll
    for (int s = 0; s < 4; ++s) {
      const f32x4 ha = *(const f32x4*)(zrow + s * 32 + lg * 4);
      const f32x4 hb = *(const f32x4*)(zrow + s * 32 + 16 + lg * 4);
      bf16x8 f;
      f[0] = (__bf16)ha.x; f[1] = (__bf16)ha.y; f[2] = (__bf16)ha.z; f[3] = (__bf16)ha.w;
      f[4] = (__bf16)hb.x; f[5] = (__bf16)hb.y; f[6] = (__bf16)hb.z; f[7] = (__bf16)hb.w;
      a[s] = f;
    }

    f32x4 acc[3][2] = {};
#pragma unroll
    for (int s = 0; s < 4; ++s)
#pragma unroll
      for (int m = 0; m < 3; ++m)
#pragma unroll
        for (int j = 0; j < 2; ++j)
          acc[m][j] = __builtin_amdgcn_mfma_f32_16x16x32_bf16(a[s], b[m][j][s], acc[m][j], 0, 0, 0);

    unsigned short* tS  = tblS + (size_t)p * NC;
    unsigned char*  tRs = tbl8 + (size_t)(2 * p + 0) * NC;
    unsigned char*  tRd = tbl8 + (size_t)(2 * p + 1) * NC;
#pragma unroll
    for (int r = 0; r < 4; ++r) {
      const int row = row0 + lg * 4 + r;
      const size_t o = (size_t)row * CC + col0 + 2 * l15;   // cols 2*l15, 2*l15+1

      *(unsigned*)(tS + o) = f2bf_u(acc[0][0][r]) | (f2bf_u(acc[0][1][r]) << 16);

      const int pks = __builtin_amdgcn_cvt_pk_fp8_f32(acc[1][0][r], acc[1][1][r], 0, false);
      *(unsigned short*)(tRs + o) = (unsigned short)pks;

      const int pkd = __builtin_amdgcn_cvt_pk_fp8_f32(acc[2][0][r], acc[2][1][r], 0, false);
      *(unsigned short*)(tRd + o) = (unsigned short)pkd;
    }
  }
}

// ---------------------------------------------------------------------------
// Phase 2: one wave per node, lane covers 2 cols (ushort = 2 x e4m3).
// R11 post-mortem: preheat falsified residency; the real agg slowdown is in
// the COUNTERS — VGPR_Count=24 cannot hold 21 in-flight loads, so the R9-R11
// builds re-serialized the gather batch: the memory-clobber asm orders
// memory ops only, and the register-only decode/accumulate chain was hoisted
// up between the loads (codegen perturbation by the co-compiled gemm,
// rule #19; R4-R8 builds happened to keep the batch -> ~32 µs).
// Airtight schedule: loads -> ONE memory clobber (loads can't sink below)
// -> per-value "+v" pins (volatile asms keep order with the clobber, so
// pins can't hoist above; consumers read pin outputs so they can't either).
// Validity handled by a wave-uniform bitmask computed BEFORE the loads
// (idx regs die early; sc/dc via popcount) to keep live-set ~25 regs.
// ---------------------------------------------------------------------------
__global__ __launch_bounds__(256)
void agg_kernel(const int* __restrict__ same1, const int* __restrict__ diff1,
                const int* __restrict__ same2, const int* __restrict__ diff2,
                const unsigned short* __restrict__ tblS,
                const unsigned char* __restrict__ tbl8,
                float* __restrict__ out)
{
  const int lane = threadIdx.x & 63;
  const int g    = __builtin_amdgcn_readfirstlane(blockIdx.x * 4 + (threadIdx.x >> 6));
  const int p    = (g >= NN) ? 1 : 0;
  const int node = g - p * NN;
  const int* __restrict__ same = p ? same2 : same1;
  const int* __restrict__ diff = p ? diff2 : diff1;
  const unsigned char* __restrict__ tRs = tbl8 + (size_t)(2 * p + 0) * NC;
  const unsigned char* __restrict__ tRd = tbl8 + (size_t)(2 * p + 1) * NC;

  // scalar index loads + validity mask (wave-uniform); idx dies before batch
  int idx[2 * KK];
  unsigned mask = 0;
#pragma unroll
  for (int k = 0; k < KK; ++k) {
    idx[k]      = same[node * KK + k];
    idx[KK + k] = diff[node * KK + k];
  }
#pragma unroll
  for (int i = 0; i < 2 * KK; ++i) {
    mask |= (idx[i] >= 0 ? 1u : 0u) << i;
    idx[i] = idx[i] < 0 ? 0 : idx[i];
  }
  const int sc = __builtin_popcount(mask & 0x3FFu);
  const int dc = __builtin_popcount(mask >> KK);

  // batched gathers: 21 independent loads, all issued before the clobber
  unsigned val[2 * KK];
#pragma unroll
  for (int i = 0; i < 2 * KK; ++i) {
    const unsigned char* __restrict__ t = (i < KK) ? tRs : tRd;
    val[i] = *(const unsigned short*)(t + (size_t)idx[i] * CC + lane * 2);
  }
  const size_t o = (size_t)g * CC + (size_t)(lane * 2);
  unsigned su = *(const unsigned*)(tblS + o);

  asm volatile("" ::: "memory");          // loads cannot sink below this
#pragma unroll
  for (int i = 0; i < 2 * KK; ++i)
    asm volatile("" : "+v"(val[i]));      // consumers cannot hoist above this
  asm volatile("" : "+v"(su));

  float s0 = 0.f, s1 = 0.f, d0 = 0.f, d1 = 0.f;
#pragma unroll
  for (int i = 0; i < KK; ++i) {
    const unsigned u = ((mask >> i) & 1u) ? val[i] : 0u;
    f32x2 pr = __builtin_amdgcn_cvt_pk_f32_fp8(u, false);
    s0 += pr.x; s1 += pr.y;
  }
#pragma unroll
  for (int i = KK; i < 2 * KK; ++i) {
    const unsigned u = ((mask >> i) & 1u) ? val[i] : 0u;
    f32x2 pr = __builtin_amdgcn_cvt_pk_f32_fp8(u, false);
    d0 += pr.x; d1 += pr.y;
  }

  union { unsigned u; float f; } slo, shi;
  slo.u = su << 16;
  shi.u = su & 0xFFFF0000u;

  const float fs = 1.f / (float)(sc > 0 ? sc : 1);
  const float fd = 1.f / (float)(dc > 0 ? dc : 1);
  const float vlo = slo.f + s0 * fs + d0 * fd;
  const float vhi = shi.f + s1 * fs + d1 * fd;
  f32x2 r;
  r.x = vlo > 0.f ? vlo : 0.f;
  r.y = vhi > 0.f ? vhi : 0.f;
  __builtin_nontemporal_store(r, (f32x2*)(out + o));
}

// ---------------------------------------------------------------------------
// Safety fallback if ws is too small: direct per-node recompute (slow, correct).
// ---------------------------------------------------------------------------
__global__ __launch_bounds__(128)
void fallback_kernel(const float* __restrict__ Z, const int* __restrict__ same,
                     const int* __restrict__ diff,
                     const float* __restrict__ Wsv, const float* __restrict__ Wsr,
                     const float* __restrict__ Wdr, float* __restrict__ out)
{
  const int node = blockIdx.x;
  const int c    = threadIdx.x;
  __shared__ float zs[FF];
  zs[c] = Z[(size_t)node * FF + c];
  __syncthreads();
  float sig = 0.f;
  for (int f = 0; f < FF; ++f) sig += zs[f] * Wsv[f * CC + c];

  float ssum = 0.f, dsum = 0.f;
  int scnt = 0, dcnt = 0;
  for (int k = 0; k < KK; ++k) {
    const int is = same[node * KK + k];
    if (is >= 0) {
      __syncthreads();
      zs[c] = Z[(size_t)is * FF + c];
      __syncthreads();
      float a = 0.f;
      for (int f = 0; f < FF; ++f) a += zs[f] * Wsr[f * CC + c];
      ssum += a; scnt++;
    }
  }
  for (int k = 0; k < KK; ++k) {
    const int id = diff[node * KK + k];
    if (id >= 0) {
      __syncthreads();
      zs[c] = Z[(size_t)id * FF + c];
      __syncthreads();
      float a = 0.f;
      for (int f = 0; f < FF; ++f) a += zs[f] * Wdr[f * CC + c];
      dsum += a; dcnt++;
    }
  }
  const float v = sig + ssum / (float)(scnt > 0 ? scnt : 1)
                      + dsum / (float)(dcnt > 0 ? dcnt : 1);
  out[(size_t)node * CC + c] = v > 0.f ? v : 0.f;
}

extern "C" void kernel_launch(void* const* d_in, const int* in_sizes, int n_in,
                              void* d_out, int out_size, void* d_ws, size_t ws_size,
                              hipStream_t stream)
{
  const float* Z1    = (const float*)d_in[0];
  const int*   same1 = (const int*)  d_in[1];
  const int*   diff1 = (const int*)  d_in[2];
  const float* Z2    = (const float*)d_in[3];
  const int*   same2 = (const int*)  d_in[4];
  const int*   diff2 = (const int*)  d_in[5];
  const float* Wsv   = (const float*)d_in[6];
  const float* Wsr   = (const float*)d_in[7];
  const float* Wdr   = (const float*)d_in[8];
  float* out = (float*)d_out;

  // ws layout: [ S bf16: 2*NC ushort | tables e4m3: 4*NC bytes ] = 8*NC bytes
  const size_t need = 8 * NC;
  unsigned short* tblS = (unsigned short*)d_ws;
  unsigned char*  tbl8 = (unsigned char*)d_ws + 2 * NC * sizeof(unsigned short);

  if (ws_size >= need) {
    gemm3_kernel<<<512, 256, 0, stream>>>(Z1, Z2, Wsv, Wsr, Wdr, tblS, tbl8);
    agg_kernel<<<(2 * NN) / 4, 256, 0, stream>>>(same1, diff1, same2, diff2,
                                                 tblS, tbl8, out);
  } else {
    fallback_kernel<<<NN, 128, 0, stream>>>(Z1, same1, diff1, Wsv, Wsr, Wdr, out);
    fallback_kernel<<<NN, 128, 0, stream>>>(Z2, same2, diff2, Wsv, Wsr, Wdr, out + NC);
  }
}

// Round 13
// 79.955 us; speedup vs baseline: 1.1139x; 1.0211x over previous
//
#include <hip/hip_runtime.h>
#include <cstdint>
#include <cstddef>

#define NN 50000
#define FF 128
#define CC 128
#define KK 10

constexpr int TILES_P = NN / 16;            // 3125 row-tiles per protein
constexpr size_t NC = (size_t)NN * CC;      // 6.4M elements per protein

typedef __bf16 bf16x8 __attribute__((ext_vector_type(8)));
typedef float  f32x4  __attribute__((ext_vector_type(4)));
typedef float  f32x2  __attribute__((ext_vector_type(2)));

__device__ __forceinline__ unsigned f2bf_u(float f) {
  union { float f; unsigned u; } x; x.f = f;
  unsigned r = x.u + 0x7fffu + ((x.u >> 16) & 1u);   // RNE
  return r >> 16;
}

// ---------------------------------------------------------------------------
// Phase 1 (R9-exact): S = Z@Wsv -> ws (bf16); Rs,Rd -> ws (e4m3, HW cvt).
// Wide-segment stores (B-col mapping col0+2*l15+j): S = 1 dword (64B
// segments), Rs/Rd = 1 ushort (32B segments). ~25-30 µs, at traffic floor.
// ---------------------------------------------------------------------------
__global__ __launch_bounds__(256, 2)
void gemm3_kernel(const float* __restrict__ Z1, const float* __restrict__ Z2,
                  const float* __restrict__ Wsv, const float* __restrict__ Wsr,
                  const float* __restrict__ Wdr,
                  unsigned short* __restrict__ tblS, unsigned char* __restrict__ tbl8)
{
  const int tid  = threadIdx.x;
  const int wave = tid >> 6;
  const int lane = tid & 63;
  const int l15  = lane & 15;
  const int lg   = lane >> 4;
  const int col0 = wave * 32;

  const float* Wm[3] = { Wsv, Wsr, Wdr };
  bf16x8 b[3][2][4];
#pragma unroll
  for (int m = 0; m < 3; ++m) {
    const float* __restrict__ W = Wm[m];
#pragma unroll
    for (int j = 0; j < 2; ++j) {
      const int col = col0 + 2 * l15 + j;
#pragma unroll
      for (int s = 0; s < 4; ++s) {
        bf16x8 f;
#pragma unroll
        for (int e = 0; e < 8; ++e) {
          const int k = s * 32 + (e >> 2) * 16 + lg * 4 + (e & 3);
          f[e] = (__bf16)W[k * CC + col];
        }
        b[m][j][s] = f;
      }
    }
  }

  const int total = 2 * TILES_P;
  for (int t = blockIdx.x; t < total; t += gridDim.x) {
    const int p    = (t >= TILES_P) ? 1 : 0;
    const int row0 = (t - p * TILES_P) * 16;
    const float* __restrict__ Z = p ? Z2 : Z1;
    const float* zrow = Z + (size_t)(row0 + l15) * FF;

    bf16x8 a[4];
#pragma unroll
    for (int s = 0; s < 4; ++s) {
      const f32x4 ha = *(const f32x4*)(zrow + s * 32 + lg * 4);
      const f32x4 hb = *(const f32x4*)(zrow + s * 32 + 16 + lg * 4);
      bf16x8 f;
      f[0] = (__bf16)ha.x; f[1] = (__bf16)ha.y; f[2] = (__bf16)ha.z; f[3] = (__bf16)ha.w;
      f[4] = (__bf16)hb.x; f[5] = (__bf16)hb.y; f[6] = (__bf16)hb.z; f[7] = (__bf16)hb.w;
      a[s] = f;
    }

    f32x4 acc[3][2] = {};
#pragma unroll
    for (int s = 0; s < 4; ++s)
#pragma unroll
      for (int m = 0; m < 3; ++m)
#pragma unroll
        for (int j = 0; j < 2; ++j)
          acc[m][j] = __builtin_amdgcn_mfma_f32_16x16x32_bf16(a[s], b[m][j][s], acc[m][j], 0, 0, 0);

    unsigned short* tS  = tblS + (size_t)p * NC;
    unsigned char*  tRs = tbl8 + (size_t)(2 * p + 0) * NC;
    unsigned char*  tRd = tbl8 + (size_t)(2 * p + 1) * NC;
#pragma unroll
    for (int r = 0; r < 4; ++r) {
      const int row = row0 + lg * 4 + r;
      const size_t o = (size_t)row * CC + col0 + 2 * l15;   // cols 2*l15, 2*l15+1

      *(unsigned*)(tS + o) = f2bf_u(acc[0][0][r]) | (f2bf_u(acc[0][1][r]) << 16);

      const int pks = __builtin_amdgcn_cvt_pk_fp8_f32(acc[1][0][r], acc[1][1][r], 0, false);
      *(unsigned short*)(tRs + o) = (unsigned short)pks;

      const int pkd = __builtin_amdgcn_cvt_pk_fp8_f32(acc[2][0][r], acc[2][1][r], 0, false);
      *(unsigned short*)(tRd + o) = (unsigned short)pkd;
    }
  }
}

// ---------------------------------------------------------------------------
// Phase 2: one wave per node, lane covers 2 cols (ushort = 2 x e4m3).
// R12 post-mortem: HIP-level pins left VGPR=24 — compiler d16-packs or
// spill-serializes around any source-level fence (scratch doesn't alias the
// "memory" clobber). So the gather batch is now INLINE ASM: 2 blocks of
// 10 x global_load_ushort (early-clobber dests; saddr = table base SGPR
// pair, voffset = idx*128+lane*2), then one asm s_waitcnt vmcnt(0) carrying
// all 20 values as "+v" — consumers are data-dependent on its outputs, so
// no hoisting (rule 18 via data dep). Forces 20 full VGPRs + single wait.
// ---------------------------------------------------------------------------
__global__ __launch_bounds__(256)
void agg_kernel(const int* __restrict__ same1, const int* __restrict__ diff1,
                const int* __restrict__ same2, const int* __restrict__ diff2,
                const unsigned short* __restrict__ tblS,
                const unsigned char* __restrict__ tbl8,
                float* __restrict__ out)
{
  const int lane = threadIdx.x & 63;
  const int g    = __builtin_amdgcn_readfirstlane(blockIdx.x * 4 + (threadIdx.x >> 6));
  const int p    = (g >= NN) ? 1 : 0;
  const int node = g - p * NN;
  const int* __restrict__ same = p ? same2 : same1;
  const int* __restrict__ diff = p ? diff2 : diff1;
  const unsigned char* __restrict__ tRs = tbl8 + (size_t)(2 * p + 0) * NC;
  const unsigned char* __restrict__ tRd = tbl8 + (size_t)(2 * p + 1) * NC;

  // scalar index loads + validity mask; byte offsets (row = 128 B)
  int idx[2 * KK];
  unsigned mask = 0;
#pragma unroll
  for (int k = 0; k < KK; ++k) {
    idx[k]      = same[node * KK + k];
    idx[KK + k] = diff[node * KK + k];
  }
  unsigned off[2 * KK];
#pragma unroll
  for (int i = 0; i < 2 * KK; ++i) {
    mask |= (idx[i] >= 0 ? 1u : 0u) << i;
    const unsigned ic = (unsigned)(idx[i] < 0 ? 0 : idx[i]);
    off[i] = ic * (unsigned)CC + (unsigned)(lane * 2);
  }
  const int sc = __builtin_popcount(mask & 0x3FFu);
  const int dc = __builtin_popcount(mask >> KK);

  const size_t o = (size_t)g * CC + (size_t)(lane * 2);
  const unsigned su = *(const unsigned*)(tblS + o);

  unsigned val[2 * KK];
  // batch 1: 10 gathers from Rs table
  asm volatile(
    "global_load_ushort %0, %10, %20\n\t"
    "global_load_ushort %1, %11, %20\n\t"
    "global_load_ushort %2, %12, %20\n\t"
    "global_load_ushort %3, %13, %20\n\t"
    "global_load_ushort %4, %14, %20\n\t"
    "global_load_ushort %5, %15, %20\n\t"
    "global_load_ushort %6, %16, %20\n\t"
    "global_load_ushort %7, %17, %20\n\t"
    "global_load_ushort %8, %18, %20\n\t"
    "global_load_ushort %9, %19, %20"
    : "=&v"(val[0]), "=&v"(val[1]), "=&v"(val[2]), "=&v"(val[3]), "=&v"(val[4]),
      "=&v"(val[5]), "=&v"(val[6]), "=&v"(val[7]), "=&v"(val[8]), "=&v"(val[9])
    : "v"(off[0]), "v"(off[1]), "v"(off[2]), "v"(off[3]), "v"(off[4]),
      "v"(off[5]), "v"(off[6]), "v"(off[7]), "v"(off[8]), "v"(off[9]),
      "s"(tRs));
  // batch 2: 10 gathers from Rd table
  asm volatile(
    "global_load_ushort %0, %10, %20\n\t"
    "global_load_ushort %1, %11, %20\n\t"
    "global_load_ushort %2, %12, %20\n\t"
    "global_load_ushort %3, %13, %20\n\t"
    "global_load_ushort %4, %14, %20\n\t"
    "global_load_ushort %5, %15, %20\n\t"
    "global_load_ushort %6, %16, %20\n\t"
    "global_load_ushort %7, %17, %20\n\t"
    "global_load_ushort %8, %18, %20\n\t"
    "global_load_ushort %9, %19, %20"
    : "=&v"(val[10]), "=&v"(val[11]), "=&v"(val[12]), "=&v"(val[13]), "=&v"(val[14]),
      "=&v"(val[15]), "=&v"(val[16]), "=&v"(val[17]), "=&v"(val[18]), "=&v"(val[19])
    : "v"(off[10]), "v"(off[11]), "v"(off[12]), "v"(off[13]), "v"(off[14]),
      "v"(off[15]), "v"(off[16]), "v"(off[17]), "v"(off[18]), "v"(off[19]),
      "s"(tRd));
  // single drain; consumers are data-dependent on these outputs
  asm volatile(
    "s_waitcnt vmcnt(0)"
    : "+v"(val[0]),  "+v"(val[1]),  "+v"(val[2]),  "+v"(val[3]),  "+v"(val[4]),
      "+v"(val[5]),  "+v"(val[6]),  "+v"(val[7]),  "+v"(val[8]),  "+v"(val[9]),
      "+v"(val[10]), "+v"(val[11]), "+v"(val[12]), "+v"(val[13]), "+v"(val[14]),
      "+v"(val[15]), "+v"(val[16]), "+v"(val[17]), "+v"(val[18]), "+v"(val[19]));

  float s0 = 0.f, s1 = 0.f, d0 = 0.f, d1 = 0.f;
#pragma unroll
  for (int i = 0; i < KK; ++i) {
    const unsigned u = ((mask >> i) & 1u) ? val[i] : 0u;
    f32x2 pr = __builtin_amdgcn_cvt_pk_f32_fp8(u, false);
    s0 += pr.x; s1 += pr.y;
  }
#pragma unroll
  for (int i = KK; i < 2 * KK; ++i) {
    const unsigned u = ((mask >> i) & 1u) ? val[i] : 0u;
    f32x2 pr = __builtin_amdgcn_cvt_pk_f32_fp8(u, false);
    d0 += pr.x; d1 += pr.y;
  }

  union { unsigned u; float f; } slo, shi;
  slo.u = su << 16;
  shi.u = su & 0xFFFF0000u;

  const float fs = 1.f / (float)(sc > 0 ? sc : 1);
  const float fd = 1.f / (float)(dc > 0 ? dc : 1);
  const float vlo = slo.f + s0 * fs + d0 * fd;
  const float vhi = shi.f + s1 * fs + d1 * fd;
  f32x2 r;
  r.x = vlo > 0.f ? vlo : 0.f;
  r.y = vhi > 0.f ? vhi : 0.f;
  __builtin_nontemporal_store(r, (f32x2*)(out + o));
}

// ---------------------------------------------------------------------------
// Safety fallback if ws is too small: direct per-node recompute (slow, correct).
// ---------------------------------------------------------------------------
__global__ __launch_bounds__(128)
void fallback_kernel(const float* __restrict__ Z, const int* __restrict__ same,
                     const int* __restrict__ diff,
                     const float* __restrict__ Wsv, const float* __restrict__ Wsr,
                     const float* __restrict__ Wdr, float* __restrict__ out)
{
  const int node = blockIdx.x;
  const int c    = threadIdx.x;
  __shared__ float zs[FF];
  zs[c] = Z[(size_t)node * FF + c];
  __syncthreads();
  float sig = 0.f;
  for (int f = 0; f < FF; ++f) sig += zs[f] * Wsv[f * CC + c];

  float ssum = 0.f, dsum = 0.f;
  int scnt = 0, dcnt = 0;
  for (int k = 0; k < KK; ++k) {
    const int is = same[node * KK + k];
    if (is >= 0) {
      __syncthreads();
      zs[c] = Z[(size_t)is * FF + c];
      __syncthreads();
      float a = 0.f;
      for (int f = 0; f < FF; ++f) a += zs[f] * Wsr[f * CC + c];
      ssum += a; scnt++;
    }
  }
  for (int k = 0; k < KK; ++k) {
    const int id = diff[node * KK + k];
    if (id >= 0) {
      __syncthreads();
      zs[c] = Z[(size_t)id * FF + c];
      __syncthreads();
      float a = 0.f;
      for (int f = 0; f < FF; ++f) a += zs[f] * Wdr[f * CC + c];
      dsum += a; dcnt++;
    }
  }
  const float v = sig + ssum / (float)(scnt > 0 ? scnt : 1)
                      + dsum / (float)(dcnt > 0 ? dcnt : 1);
  out[(size_t)node * CC + c] = v > 0.f ? v : 0.f;
}

extern "C" void kernel_launch(void* const* d_in, const int* in_sizes, int n_in,
                              void* d_out, int out_size, void* d_ws, size_t ws_size,
                              hipStream_t stream)
{
  const float* Z1    = (const float*)d_in[0];
  const int*   same1 = (const int*)  d_in[1];
  const int*   diff1 = (const int*)  d_in[2];
  const float* Z2    = (const float*)d_in[3];
  const int*   same2 = (const int*)  d_in[4];
  const int*   diff2 = (const int*)  d_in[5];
  const float* Wsv   = (const float*)d_in[6];
  const float* Wsr   = (const float*)d_in[7];
  const float* Wdr   = (const float*)d_in[8];
  float* out = (float*)d_out;

  // ws layout: [ S bf16: 2*NC ushort | tables e4m3: 4*NC bytes ] = 8*NC bytes
  const size_t need = 8 * NC;
  unsigned short* tblS = (unsigned short*)d_ws;
  unsigned char*  tbl8 = (unsigned char*)d_ws + 2 * NC * sizeof(unsigned short);

  if (ws_size >= need) {
    gemm3_kernel<<<512, 256, 0, stream>>>(Z1, Z2, Wsv, Wsr, Wdr, tblS, tbl8);
    agg_kernel<<<(2 * NN) / 4, 256, 0, stream>>>(same1, diff1, same2, diff2,
                                                 tblS, tbl8, out);
  } else {
    fallback_kernel<<<NN, 128, 0, stream>>>(Z1, same1, diff1, Wsv, Wsr, Wdr, out);
    fallback_kernel<<<NN, 128, 0, stream>>>(Z2, same2, diff2, Wsv, Wsr, Wdr, out + NC);
  }
}